// Round 5
// baseline (70.001 us; speedup 1.0000x reference)
//
#include <hip/hip_runtime.h>

// GARCH(1,1) paths, 3 series, N = 24*131072.
//   v_t = omega + alpha*p_{t-1}^2 + beta*v_{t-1};  p_t = mu + z_t*sqrt(v_t); p_0=0.
// out[s*N + t] = p_t.
//
// R4 = R3 with one fix: the exact-replay path (first block of EVERY series,
// b==0, not just bid==0) must write to out + s*N, not out. R3 left series 1/2
// heads unwritten (absmax 0.84 = max|p| there).
//
// Structure:
//  - Block covers TILE=16384 outputs; thread tid owns [B0+128*tid, +128),
//    warmed up WARM=512 steps from the steady-state guess (contraction:
//    ~1e-4 relative v error even at +5 sigma worst-case params).
//  - Whole window z[B0-512 .. B0+16384) staged in LDS TRANSPOSED:
//    window elem j at W[(j&127)*133 + (j>>7)]. Thread tid at step k reads
//    j=128*tid+k -> row k&127 (wave-uniform), col tid+(k>>7): 64 consecutive
//    dwords per wave => bank-conflict-free ds_read_b32.
//  - Chain-shortened recurrence (exact algebra):
//      v_t = w0 + c1(z_{t-1})*sqrt(v_{t-1}) + c2(z_{t-1})*v_{t-1},
//      c1 = 2*alpha*mu*z, c2 = alpha*z^2 + beta, w0 = omega + alpha*mu^2.
//    c1,c2 off the dependent chain; chain = fma -> (fma || sqrt).
//    p materialized only in the 128-step output phase: p_t = fma(z_t, sv, mu).

#define NSER 3
#define KOUT 128
#define BT   128
#define TILE (BT * KOUT)      // 16384
#define WARM 512
#define WIN  (TILE + WARM)    // 16896 floats
#define LSTR 133              // LDS row stride (132 cols + 1 pad)

__global__ __launch_bounds__(BT) void garch_kernel(
    const float* __restrict__ params,   // (3,4): [mu, omega, alpha, beta]
    const float* __restrict__ noise,    // (3,N)
    float* __restrict__ out,            // (3,N)
    int N)
{
    __shared__ float W[128 * LSTR];     // 68,096 B -> 2 blocks/CU

    const int nblk = N / TILE;          // 192 blocks per series
    const int bid  = blockIdx.x;
    const int s    = bid / nblk;
    const int b    = bid - s * nblk;
    const int tid  = threadIdx.x;
    const int B0   = b * TILE;

    const float mu    = params[s * 4 + 0];
    const float omega = params[s * 4 + 1];
    const float alpha = params[s * 4 + 2];
    const float beta  = params[s * 4 + 3];

    const float4* z4 = (const float4*)(noise + (size_t)s * N);

    // ---- stage window z[B0-WARM .. B0+TILE) into transposed LDS ----
    {
        const int gq0 = (B0 - WARM) >> 2;          // negative only for b==0
        #pragma unroll 8
        for (int i = 0; i < WIN / 4 / BT; ++i) {   // 33 float4s per thread
            int jq = i * BT + tid;
            int gq = gq0 + jq; gq = max(gq, 0);    // clamp; clamped slots unread
            float4 val = z4[gq];                   // coalesced global read
            int j = jq << 2;                       // quad stays in one column
            float* base = &W[(j & 127) * LSTR + (j >> 7)];
            base[0*LSTR] = val.x; base[1*LSTR] = val.y;
            base[2*LSTR] = val.z; base[3*LSTR] = val.w;
        }
    }
    __syncthreads();

    // ---- exact replay for windows crossing t=0 (b==0, tid<=4) ----
    if (b == 0 && tid * KOUT <= WARM) {
        float p = 0.0f, v = 0.0f;
        float* o = out + (size_t)s * N;            // FIX: per-series base
        const int T0 = tid * KOUT;
        if (tid == 0) o[0] = 0.0f;
        for (int t = 1; t < T0 + KOUT; ++t) {
            int j = t + WARM;                      // W[j] == z[t]
            float z = W[(j & 127) * LSTR + (j >> 7)];
            v = fmaf(alpha, p * p, fmaf(beta, v, omega));
            p = fmaf(z, __builtin_amdgcn_sqrtf(v), mu);
            if (t >= T0) o[t] = p;
        }
        return;
    }

    // ---- main scan: 512 warm + 128 output steps, all from LDS ----
    const float w0 = fmaf(alpha, mu * mu, omega);
    const float k1 = 2.0f * alpha * mu;

    float v   = omega / fmaxf(1.0f - alpha - beta, 0.02f);   // steady-state guess
    float sv  = __builtin_amdgcn_sqrtf(v);
    float zc1 = 0.0f, zc2 = alpha + beta;                    // guess coeffs

    int a = tid;                       // addr of (row k&127, col tid + (k>>7))

    #define STEPV(Z) do {                                    \
        float _z = (Z);                                      \
        v   = fmaf(zc1, sv, fmaf(zc2, v, w0));               \
        sv  = __builtin_amdgcn_sqrtf(v);                     \
        zc1 = k1 * _z;                                       \
        zc2 = fmaf(alpha, _z * _z, beta);                    \
    } while (0)

    #pragma unroll 1
    for (int g = 0; g < 4; ++g) {                  // 4 x 128 = 512 warm steps
        #pragma unroll 4
        for (int r = 0; r < 128; r += 4) {
            float z0 = W[a];            float z1 = W[a + LSTR];
            float z2 = W[a + 2*LSTR];   float z3 = W[a + 3*LSTR];
            a += 4 * LSTR;
            STEPV(z0); STEPV(z1); STEPV(z2); STEPV(z3);
        }
        a -= 128 * LSTR - 1;                       // next col, row 0
    }

    float4* o4 = (float4*)(out + (size_t)s * N + B0) + 32 * tid;
    #pragma unroll 4
    for (int r = 0; r < 128; r += 4) {             // 128 output steps
        float z0 = W[a];            float z1 = W[a + LSTR];
        float z2 = W[a + 2*LSTR];   float z3 = W[a + 3*LSTR];
        a += 4 * LSTR;
        float4 pq;
        STEPV(z0); pq.x = fmaf(z0, sv, mu);
        STEPV(z1); pq.y = fmaf(z1, sv, mu);
        STEPV(z2); pq.z = fmaf(z2, sv, mu);
        STEPV(z3); pq.w = fmaf(z3, sv, mu);
        o4[r >> 2] = pq;
    }
    #undef STEPV
}

extern "C" void kernel_launch(void* const* d_in, const int* in_sizes, int n_in,
                              void* d_out, int out_size, void* d_ws, size_t ws_size,
                              hipStream_t stream) {
    const float* params = (const float*)d_in[0];
    const float* noise  = (const float*)d_in[1];
    float* out = (float*)d_out;

    const int N = in_sizes[1] / NSER;       // 3,145,728
    const int grid = NSER * (N / TILE);     // 576 blocks

    garch_kernel<<<grid, BT, 0, stream>>>(params, noise, out, N);
}

// Round 6
// 38.934 us; speedup vs baseline: 1.7980x; 1.7980x over previous
//
#include <hip/hip_runtime.h>

// GARCH(1,1) paths, 3 series, N = 24*131072.
//   v_t = omega + alpha*p_{t-1}^2 + beta*v_{t-1};  p_t = mu + z_t*sqrt(v_t); p_0=0.
// out[s*N + t] = p_t.
//
// R5:
//  - TILE=8192 (BT=128, KOUT=64, WARM=512): LDS 34,816 B -> 4 blocks/CU
//    = 8 waves/CU = 2 waves/SIMD (R4's 68KB gave 1/SIMD: latency fully exposed).
//  - Float4-transposed LDS: quad Q of the window at W[(Q&127)*68 + 4*(Q>>7)].
//    Thread tid's scan group g reads quad Q=16*tid+g: 8 rows x 8 lanes x 32
//    consecutive dwords = uniform 8 dwords/bank -> full-rate ds_read_b128,
//    ONE LDS read per 4 steps. Staging writes are also uniform 8/bank.
//  - Chain-shortened recurrence (exact algebra):
//      v_t = w0 + c1(z_{t-1})*sv_{t-1} + c2(z_{t-1})*v_{t-1}, sv = sqrt(v),
//      c1 = 2*alpha*mu*z, c2 = alpha*z^2 + beta, w0 = omega + alpha*mu^2.
//    Critical path = 2 fma/step (sqrt has a full step of slack).
//  - Head block (bid 0): 3 lanes compute outputs [0,576) per series exactly
//    from (p,v)=(0,0), z register-prefetched depth-4 from global. Removes
//    R4's ~35us masked-serial divergent replay tail. Tile lanes whose warm
//    window crosses t=0 early-exit (their outputs are the head's).

#define NSER 3
#define KOUT 64
#define BT   128
#define TILE (BT * KOUT)          // 8192
#define WARM 512
#define WIN  (TILE + WARM)        // 8704 floats
#define WINQ (WIN / 4)            // 2176 quads
#define NG   ((WARM + KOUT) / 4)  // 144 scan groups per thread
#define OUTG (WARM / 4)           // 128: first output group
#define LSTR 68                   // dwords per LDS row (multiple of 4)
#define HEADN (WARM + KOUT)       // 576 outputs covered by head block

__device__ __forceinline__ int qaddr(int Q) {        // dword address of quad Q
    return (Q & 127) * LSTR + ((Q >> 7) << 2);
}

__global__ __launch_bounds__(BT) void garch_kernel(
    const float* __restrict__ params,   // (3,4): [mu, omega, alpha, beta]
    const float* __restrict__ noise,    // (3,N)
    float* __restrict__ out,            // (3,N)
    int N)
{
    const int bid = blockIdx.x;
    const int tid = threadIdx.x;

    // ---------------- head block: outputs [0, 576) of each series ----------
    if (bid == 0) {
        if (tid < NSER) {
            const int s = tid;
            const float mu    = params[s * 4 + 0];
            const float omega = params[s * 4 + 1];
            const float alpha = params[s * 4 + 2];
            const float beta  = params[s * 4 + 3];
            const float4* zq4 = (const float4*)(noise + (size_t)s * N);
            float4*       oq4 = (float4*)(out + (size_t)s * N);

            float4 A = zq4[0], B = zq4[1], C = zq4[2], D = zq4[3];
            float p = 0.0f, v = 0.0f;

            #define HSTEP(Z) do {                                          \
                v = fmaf(alpha, p * p, fmaf(beta, v, omega));              \
                p = fmaf((Z), __builtin_amdgcn_sqrtf(v), mu);              \
            } while (0)

            // group 0: t = 0..3 (p_0 = 0)
            {
                float4 pq; pq.x = 0.0f;
                HSTEP(A.y); pq.y = p;
                HSTEP(A.z); pq.z = p;
                HSTEP(A.w); pq.w = p;
                oq4[0] = pq;
            }
            for (int m = 1; m < HEADN / 4; ++m) {   // groups 1..143
                A = B; B = C; C = D;
                D = zq4[min(m + 3, HEADN / 4 - 1)];
                float4 zq = A, pq;
                HSTEP(zq.x); pq.x = p;
                HSTEP(zq.y); pq.y = p;
                HSTEP(zq.z); pq.z = p;
                HSTEP(zq.w); pq.w = p;
                oq4[m] = pq;
            }
            #undef HSTEP
        }
        return;                                     // no barriers in this path
    }

    // ---------------- tile blocks ------------------------------------------
    __shared__ __align__(16) float W[128 * LSTR];   // 34,816 B -> 4 blocks/CU

    const int nblk = N / TILE;                      // 384 per series
    const int s    = (bid - 1) / nblk;
    const int b    = (bid - 1) - s * nblk;
    const int B0   = b * TILE;

    const float mu    = params[s * 4 + 0];
    const float omega = params[s * 4 + 1];
    const float alpha = params[s * 4 + 2];
    const float beta  = params[s * 4 + 3];

    const float4* z4 = (const float4*)(noise + (size_t)s * N);

    // ---- stage window z[B0-WARM .. B0+TILE) into float4-transposed LDS ----
    {
        const int gq0 = (B0 >> 2) - (WARM >> 2);    // negative only for b==0
        #pragma unroll
        for (int i = 0; i < WINQ / BT; ++i) {       // 17 quads per thread
            int q  = i * BT + tid;
            int gq = max(gq0 + q, 0);               // clamped slots never read
            float4 val = z4[gq];
            *(float4*)&W[qaddr(q)] = val;
        }
    }
    __syncthreads();

    // lanes whose warm window crosses t=0: outputs covered by the head block
    if (b == 0 && (tid + 1) * KOUT <= HEADN) return;   // tid <= 8, masked idle

    // ---- scan: 512 warm + 64 output steps, b128 reads, short chain --------
    const float w0 = fmaf(alpha, mu * mu, omega);
    const float k1 = 2.0f * alpha * mu;

    float v   = omega / fmaxf(1.0f - alpha - beta, 0.02f);   // steady-state
    float sv  = __builtin_amdgcn_sqrtf(v);
    float zc1 = 0.0f, zc2 = alpha + beta;

    const int Qb = 16 * tid;

    #define LDQ(G) (*(const float4*)&W[qaddr(min(Qb + (G), WINQ - 1))])
    #define STEPV(Z) do {                                    \
        float _z = (Z);                                      \
        v   = fmaf(zc1, sv, fmaf(zc2, v, w0));               \
        sv  = __builtin_amdgcn_sqrtf(v);                     \
        zc1 = k1 * _z;                                       \
        zc2 = fmaf(alpha, _z * _z, beta);                    \
    } while (0)

    float4 qa = LDQ(0);
    float4 qb = LDQ(1);

    #pragma unroll 4
    for (int g = 0; g < OUTG; ++g) {                // 128 warm groups
        float4 qn = LDQ(g + 2);
        STEPV(qa.x); STEPV(qa.y); STEPV(qa.z); STEPV(qa.w);
        qa = qb; qb = qn;
    }

    float4* o4 = (float4*)(out + (size_t)s * N + B0) + 16 * tid - OUTG;
    #pragma unroll
    for (int g = OUTG; g < NG; ++g) {               // 16 output groups
        float4 qn = LDQ(g + 2);
        float4 pq;
        STEPV(qa.x); pq.x = fmaf(qa.x, sv, mu);
        STEPV(qa.y); pq.y = fmaf(qa.y, sv, mu);
        STEPV(qa.z); pq.z = fmaf(qa.z, sv, mu);
        STEPV(qa.w); pq.w = fmaf(qa.w, sv, mu);
        o4[g] = pq;
        qa = qb; qb = qn;
    }
    #undef STEPV
    #undef LDQ
}

extern "C" void kernel_launch(void* const* d_in, const int* in_sizes, int n_in,
                              void* d_out, int out_size, void* d_ws, size_t ws_size,
                              hipStream_t stream) {
    const float* params = (const float*)d_in[0];
    const float* noise  = (const float*)d_in[1];
    float* out = (float*)d_out;

    const int N = in_sizes[1] / NSER;       // 3,145,728
    const int grid = 1 + NSER * (N / TILE); // 1 head + 1152 tile blocks

    garch_kernel<<<grid, BT, 0, stream>>>(params, noise, out, N);
}

// Round 7
// 37.479 us; speedup vs baseline: 1.8678x; 1.0388x over previous
//
#include <hip/hip_runtime.h>

// GARCH(1,1) paths, 3 series, N = 24*131072.
//   v_t = omega + alpha*p_{t-1}^2 + beta*v_{t-1};  p_t = mu + z_t*sqrt(v_t); p_0=0.
// out[s*N + t] = p_t.
//
// R6 = R5 with ONE change: flat padded-slot LDS layout.
//   Window quad Q lives at 16B slot s(Q) = Q + (Q>>4)  (pad slot every 16).
//   Scan read, lane tid, group g: Q=16*tid+g -> s = 17*tid + g + (g>>4):
//     every 8-lane phase hits all 8 bank-quads once -> conflict-free b128.
//   Staging write q=128*i+tid -> s = 144*i + tid + (tid>>4): also uniform.
//   (R5's 2-D layout put all 8 lanes of each phase in bank-quad 0: 6.3M
//    conflict cycles ~ 17 extra cy/read. Lane-order phase model.)
//   LDS 37,088 B -> still 4 blocks/CU = 8 waves/CU.
//
// Kept from R5:
//  - TILE=8192 (BT=128, KOUT=64, WARM=512); contraction washes out the
//    steady-state-guess error (~1e-4 rel v at +5 sigma worst case).
//  - Chain-shortened recurrence (exact algebra):
//      v_t = w0 + c1(z)*sv + c2(z)*v,  sv=sqrt(v),
//      c1=2*alpha*mu*z, c2=alpha*z^2+beta, w0=omega+alpha*mu^2.
//  - Head block computes outputs [0,576) exactly; b==0 early-window lanes exit.

#define NSER 3
#define KOUT 64
#define BT   128
#define TILE (BT * KOUT)          // 8192
#define WARM 512
#define WIN  (TILE + WARM)        // 8704 floats
#define WINQ (WIN / 4)            // 2176 quads
#define NG   ((WARM + KOUT) / 4)  // 144 scan groups per thread
#define OUTG (WARM / 4)           // 128: first output group
#define HEADN (WARM + KOUT)       // 576 outputs covered by head block
#define QMAX (16 * (BT - 1) + NG + 1)        // deepest prefetched quad: 2177
#define NSLOT (QMAX + (QMAX >> 4) + 2)       // 2315 slots

__device__ __forceinline__ int qslot(int Q) { return Q + (Q >> 4); }

__global__ __launch_bounds__(BT) void garch_kernel(
    const float* __restrict__ params,   // (3,4): [mu, omega, alpha, beta]
    const float* __restrict__ noise,    // (3,N)
    float* __restrict__ out,            // (3,N)
    int N)
{
    const int bid = blockIdx.x;
    const int tid = threadIdx.x;

    // ---------------- head block: outputs [0, 576) of each series ----------
    if (bid == 0) {
        if (tid < NSER) {
            const int s = tid;
            const float mu    = params[s * 4 + 0];
            const float omega = params[s * 4 + 1];
            const float alpha = params[s * 4 + 2];
            const float beta  = params[s * 4 + 3];
            const float4* zq4 = (const float4*)(noise + (size_t)s * N);
            float4*       oq4 = (float4*)(out + (size_t)s * N);

            float4 A = zq4[0], B = zq4[1], C = zq4[2], D = zq4[3];
            float p = 0.0f, v = 0.0f;

            #define HSTEP(Z) do {                                          \
                v = fmaf(alpha, p * p, fmaf(beta, v, omega));              \
                p = fmaf((Z), __builtin_amdgcn_sqrtf(v), mu);              \
            } while (0)

            {
                float4 pq; pq.x = 0.0f;                 // p_0 = 0
                HSTEP(A.y); pq.y = p;
                HSTEP(A.z); pq.z = p;
                HSTEP(A.w); pq.w = p;
                oq4[0] = pq;
            }
            for (int m = 1; m < HEADN / 4; ++m) {
                A = B; B = C; C = D;
                D = zq4[min(m + 3, HEADN / 4 - 1)];
                float4 zq = A, pq;
                HSTEP(zq.x); pq.x = p;
                HSTEP(zq.y); pq.y = p;
                HSTEP(zq.z); pq.z = p;
                HSTEP(zq.w); pq.w = p;
                oq4[m] = pq;
            }
            #undef HSTEP
        }
        return;
    }

    // ---------------- tile blocks ------------------------------------------
    __shared__ __align__(16) float4 Wq[NSLOT];      // 37,040 B -> 4 blocks/CU

    const int nblk = N / TILE;                      // 384 per series
    const int s    = (bid - 1) / nblk;
    const int b    = (bid - 1) - s * nblk;
    const int B0   = b * TILE;

    const float mu    = params[s * 4 + 0];
    const float omega = params[s * 4 + 1];
    const float alpha = params[s * 4 + 2];
    const float beta  = params[s * 4 + 3];

    const float4* z4 = (const float4*)(noise + (size_t)s * N);

    // ---- stage window z[B0-WARM .. B0+TILE) into padded-slot LDS ----------
    {
        const int gq0 = (B0 >> 2) - (WARM >> 2);    // negative only for b==0
        #pragma unroll
        for (int i = 0; i < WINQ / BT; ++i) {       // 17 quads per thread
            int q  = i * BT + tid;
            int gq = max(gq0 + q, 0);               // clamped slots never read
            Wq[qslot(q)] = z4[gq];
        }
        if (tid < 2) Wq[qslot(WINQ + tid)] = z4[0]; // pad quads for prefetch
    }
    __syncthreads();

    // lanes whose warm window crosses t=0: outputs covered by the head block
    if (b == 0 && (tid + 1) * KOUT <= HEADN) return;

    // ---- scan: 512 warm + 64 output steps ---------------------------------
    const float w0 = fmaf(alpha, mu * mu, omega);
    const float k1 = 2.0f * alpha * mu;

    float v   = omega / fmaxf(1.0f - alpha - beta, 0.02f);   // steady-state
    float sv  = __builtin_amdgcn_sqrtf(v);
    float zc1 = 0.0f, zc2 = alpha + beta;

    const int Qb = 16 * tid;

    #define LDQ(G) (Wq[qslot(Qb + (G))])
    #define STEPV(Z) do {                                    \
        float _z = (Z);                                      \
        v   = fmaf(zc1, sv, fmaf(zc2, v, w0));               \
        sv  = __builtin_amdgcn_sqrtf(v);                     \
        zc1 = k1 * _z;                                       \
        zc2 = fmaf(alpha, _z * _z, beta);                    \
    } while (0)

    float4 qa = LDQ(0);
    float4 qb = LDQ(1);

    #pragma unroll 4
    for (int g = 0; g < OUTG; ++g) {                // 128 warm groups
        float4 qn = LDQ(g + 2);
        STEPV(qa.x); STEPV(qa.y); STEPV(qa.z); STEPV(qa.w);
        qa = qb; qb = qn;
    }

    float4* o4 = (float4*)(out + (size_t)s * N + B0) + 16 * tid - OUTG;
    #pragma unroll
    for (int g = OUTG; g < NG; ++g) {               // 16 output groups
        float4 qn = LDQ(g + 2);
        float4 pq;
        STEPV(qa.x); pq.x = fmaf(qa.x, sv, mu);
        STEPV(qa.y); pq.y = fmaf(qa.y, sv, mu);
        STEPV(qa.z); pq.z = fmaf(qa.z, sv, mu);
        STEPV(qa.w); pq.w = fmaf(qa.w, sv, mu);
        o4[g] = pq;
        qa = qb; qb = qn;
    }
    #undef STEPV
    #undef LDQ
}

extern "C" void kernel_launch(void* const* d_in, const int* in_sizes, int n_in,
                              void* d_out, int out_size, void* d_ws, size_t ws_size,
                              hipStream_t stream) {
    const float* params = (const float*)d_in[0];
    const float* noise  = (const float*)d_in[1];
    float* out = (float*)d_out;

    const int N = in_sizes[1] / NSER;       // 3,145,728
    const int grid = 1 + NSER * (N / TILE); // 1 head + 1152 tile blocks

    garch_kernel<<<grid, BT, 0, stream>>>(params, noise, out, N);
}